// Round 8
// baseline (283.394 us; speedup 1.0000x reference)
//
#include <hip/hip_runtime.h>
#include <math.h>

// SoftPeakAwareLoss on MI355X — R7: 4-lanes/day + DPP quad butterflies +
// explicit register double-buffer pipeline.
// R6 evidence: launch_bounds(256,4) left VGPR at 60 -> compiler's minimal-
// pressure schedule serializes every load batch and every "independent" body;
// kernel is serial-latency bound (1 load in flight/wave, 35-cyc shfl chains).
// R7 forces overlap structurally: per-thread state ~18 regs (6h per lane),
// butterflies are VALU-speed DPP quad_perms (4 cyc vs 35), and a 2x-unrolled
// grid-stride loop prefetches the next iteration's 9 float2 loads before
// computing the current one (alternating named buffers, no copies).

#define HOURS_ 24
#define WIN_ 2
#define NEGV (-1e9f)

__device__ __forceinline__ float frcp(float x) { return __builtin_amdgcn_rcpf(x); }

#define DPP_XOR1 0xB1   // quad_perm [1,0,3,2]
#define DPP_XOR2 0x4E   // quad_perm [2,3,0,1]

template<int CTRL>
__device__ __forceinline__ int dpp_i(int src) {
    return __builtin_amdgcn_update_dpp(0, src, CTRL, 0xF, 0xF, true);
}
template<int CTRL>
__device__ __forceinline__ float dpp_f(float x) {
    return __int_as_float(dpp_i<CTRL>(__float_as_int(x)));
}

// One day-segment (6 hours) of one day; lanes (l&3)==0..3 of a quad own
// segments 0..3 and combine via DPP butterflies.
__device__ __forceinline__ void seg_body(
    float2 p0, float2 p1, float2 p2,
    float2 t0, float2 t1, float2 t2,
    float2 m0, float2 m1, float2 m2,
    int seg, float vfl,
    float& o, float& mg, float& tl, float& sh)
{
    const int h0 = seg * 6;
    float a[6]  = {p0.x, p0.y, p1.x, p1.y, p2.x, p2.y};
    float b[6]  = {t0.x, t0.y, t1.x, t1.y, t2.x, t2.y};
    float dm[6] = {m0.x, m0.y, m1.x, m1.y, m2.x, m2.y};

    // ---- L_overall partial (own hours only)
    float oo = 0.f;
    #pragma unroll
    for (int k = 0; k < 6; ++k) { float d = a[k] - b[k]; oo = fmaf(d, d, oo); }
    o = fmaf(oo, vfl, o);

    // ---- masked values (short live ranges; recomputed where cheap)
    float bm[6], am[6];
    #pragma unroll
    for (int k = 0; k < 6; ++k) {
        bool dy = dm[k] > 0.5f;
        bm[k] = dy ? b[k] : NEGV;
        am[k] = dy ? a[k] : NEGV;
    }

    // ---- local first-occurrence argmax over 6 (ordered tree, strict >)
    bool  s0 = bm[1] > bm[0]; float v01 = s0 ? bm[1] : bm[0]; int i01 = s0 ? h0+1 : h0;
    bool  s1 = bm[3] > bm[2]; float v23 = s1 ? bm[3] : bm[2]; int i23 = s1 ? h0+3 : h0+2;
    bool  s2 = bm[5] > bm[4]; float v45 = s2 ? bm[5] : bm[4]; int i45 = s2 ? h0+5 : h0+4;
    bool  tA = v23 > v01; float mt = tA ? v23 : v01; int pk = tA ? i23 : i01;
    bool  tB = v45 > mt;  mt = tB ? v45 : mt;        pk = tB ? i45 : pk;
    float mp = fmaxf(fmaxf(fmaxf(am[0], am[1]), fmaxf(am[2], am[3])),
                     fmaxf(am[4], am[5]));

    // ---- quad butterfly (VALU-speed DPP; ties -> lower hour)
    {
        float mt_o = dpp_f<DPP_XOR1>(mt); int pk_o = dpp_i<DPP_XOR1>(pk);
        float mp_o = dpp_f<DPP_XOR1>(mp);
        bool to = (mt_o > mt) || (mt_o == mt && pk_o < pk);
        pk = to ? pk_o : pk; mt = fmaxf(mt, mt_o); mp = fmaxf(mp, mp_o);
        mt_o = dpp_f<DPP_XOR2>(mt); pk_o = dpp_i<DPP_XOR2>(pk);
        mp_o = dpp_f<DPP_XOR2>(mp);
        to = (mt_o > mt) || (mt_o == mt && pk_o < pk);
        pk = to ? pk_o : pk; mt = fmaxf(mt, mt_o); mp = fmaxf(mp, mp_o);
    }

    // ---- soft peaks: exp((x-m)*10); night -> exp(-1e10)=0
    float mt10 = mt * 10.f, mp10 = mp * 10.f;
    float set = 0.f, syt = 0.f, sht = 0.f;
    float sep = 0.f, syp = 0.f, shp = 0.f;
    #pragma unroll
    for (int k = 0; k < 6; ++k) {
        float et = __expf(fmaf(bm[k], 10.f, -mt10));
        float ep = __expf(fmaf(am[k], 10.f, -mp10));
        float hh = (float)(h0 + k);
        set += et; syt = fmaf(et, b[k], syt); sht = fmaf(et, hh, sht);
        sep += ep; syp = fmaf(ep, a[k], syp); shp = fmaf(ep, hh, shp);
    }
    set += dpp_f<DPP_XOR1>(set); set += dpp_f<DPP_XOR2>(set);
    syt += dpp_f<DPP_XOR1>(syt); syt += dpp_f<DPP_XOR2>(syt);
    sht += dpp_f<DPP_XOR1>(sht); sht += dpp_f<DPP_XOR2>(sht);
    sep += dpp_f<DPP_XOR1>(sep); sep += dpp_f<DPP_XOR2>(sep);
    syp += dpp_f<DPP_XOR1>(syp); syp += dpp_f<DPP_XOR2>(syp);
    shp += dpp_f<DPP_XOR1>(shp); shp += dpp_f<DPP_XOR2>(shp);
    {
        float rs = frcp(set), rq = frcp(sep);
        float d1 = syp * rq - syt * rs;
        float d2 = shp * rq - sht * rs;
        float once = (seg == 0) ? vfl : 0.f;   // count each day once
        mg = fmaf(d1 * d1, once, mg);
        tl = fmaf(d2 * d2, once, tl);
    }

    // ---- shape loss: window [pk-2, pk+2] clipped; analytic exact 1/cnt
    int lo = pk - WIN_; lo = lo < 0 ? 0 : lo;
    int hi = pk + WIN_; hi = hi > 23 ? 23 : hi;
    int cnt = hi - lo + 1;                      // 3,4,5
    float invcnt = (cnt == 5) ? 0.2f : ((cnt == 4) ? 0.25f : (1.f / 3.f));
    float twm = -INFINITY, pwm = -INFINITY;
    #pragma unroll
    for (int k = 0; k < 6; ++k) {
        int hg = h0 + k;
        bool in = (hg >= lo) && (hg <= hi);
        twm = in ? fmaxf(twm, b[k]) : twm;
        pwm = in ? fmaxf(pwm, a[k]) : pwm;
    }
    twm = fmaxf(twm, dpp_f<DPP_XOR1>(twm)); twm = fmaxf(twm, dpp_f<DPP_XOR2>(twm));
    pwm = fmaxf(pwm, dpp_f<DPP_XOR1>(pwm)); pwm = fmaxf(pwm, dpp_f<DPP_XOR2>(pwm));
    {
        float rt = frcp(twm + 1e-6f);
        float rp = frcp(pwm + 1e-6f);
        float ss = 0.f;
        #pragma unroll
        for (int k = 0; k < 6; ++k) {
            int hg = h0 + k;
            bool in = (hg >= lo) && (hg <= hi);
            float d = fmaf(a[k], rp, -(b[k] * rt));
            ss = in ? fmaf(d, d, ss) : ss;
        }
        // per-lane partial: sum over lanes of ss*invcnt = (window MSE)/cnt
        sh = fmaf(ss * invcnt, vfl, sh);
    }
}

__global__ __launch_bounds__(256, 6) void splloss_days(
    const float* __restrict__ ypred,
    const float* __restrict__ ytrue,
    const float* __restrict__ isday,
    float4* __restrict__ partials,
    int n_days, int nit)
{
    const int tid = threadIdx.x;
    const int seg = tid & 3;             // 6-hour segment within the day
    const int grp = tid >> 2;            // day-slot within block: 0..63
    const int dayStride = gridDim.x * 64;
    int day = blockIdx.x * 64 + grp;

    const int segOff = seg * 6;

    float o = 0.f, mg = 0.f, tl = 0.f, sh = 0.f;

    // ---- prologue: load iter 0 into buffer A
    int   dA = day < n_days ? day : 0;
    float vA = day < n_days ? 1.f : 0.f;
    const float2* pA = reinterpret_cast<const float2*>(ypred + (size_t)dA * 24 + segOff);
    const float2* tA = reinterpret_cast<const float2*>(ytrue + (size_t)dA * 24 + segOff);
    const float2* mA = reinterpret_cast<const float2*>(isday + (size_t)dA * 24 + segOff);
    float2 a0 = pA[0], a1 = pA[1], a2 = pA[2];
    float2 b0 = tA[0], b1 = tA[1], b2 = tA[2];
    float2 c0 = mA[0], c1 = mA[1], c2 = mA[2];

    for (int it = 0; it < nit; it += 2) {
        // ---- prefetch iter it+1 into buffer B (before computing A)
        int   day1 = day + dayStride;
        int   dB = day1 < n_days ? day1 : 0;
        float vB = day1 < n_days ? 1.f : 0.f;
        const float2* pB = reinterpret_cast<const float2*>(ypred + (size_t)dB * 24 + segOff);
        const float2* tB = reinterpret_cast<const float2*>(ytrue + (size_t)dB * 24 + segOff);
        const float2* mB = reinterpret_cast<const float2*>(isday + (size_t)dB * 24 + segOff);
        float2 e0 = pB[0], e1 = pB[1], e2 = pB[2];
        float2 f0 = tB[0], f1 = tB[1], f2 = tB[2];
        float2 g0 = mB[0], g1 = mB[1], g2 = mB[2];

        seg_body(a0, a1, a2, b0, b1, b2, c0, c1, c2, seg, vA, o, mg, tl, sh);

        // ---- prefetch iter it+2 into buffer A (before computing B)
        int   day2 = day + 2 * dayStride;
        int   dC = day2 < n_days ? day2 : 0;
        vA = day2 < n_days ? 1.f : 0.f;
        const float2* pC = reinterpret_cast<const float2*>(ypred + (size_t)dC * 24 + segOff);
        const float2* tC = reinterpret_cast<const float2*>(ytrue + (size_t)dC * 24 + segOff);
        const float2* mC = reinterpret_cast<const float2*>(isday + (size_t)dC * 24 + segOff);
        a0 = pC[0]; a1 = pC[1]; a2 = pC[2];
        b0 = tC[0]; b1 = tC[1]; b2 = tC[2];
        c0 = mC[0]; c1 = mC[1]; c2 = mC[2];

        seg_body(e0, e1, e2, f0, f1, f2, g0, g1, g2, seg, vB, o, mg, tl, sh);

        day = day2;
    }

    // ---- block reduction: wave shuffle then LDS across the 4 waves
    #pragma unroll
    for (int off = 32; off > 0; off >>= 1) {
        o  += __shfl_down(o,  off);
        mg += __shfl_down(mg, off);
        tl += __shfl_down(tl, off);
        sh += __shfl_down(sh, off);
    }
    __shared__ float4 red[4];
    int wid = threadIdx.x >> 6;
    if ((threadIdx.x & 63) == 0) red[wid] = make_float4(o, mg, tl, sh);
    __syncthreads();
    if (threadIdx.x == 0) {
        float4 r0 = red[0], r1 = red[1], r2 = red[2], r3 = red[3];
        partials[blockIdx.x] = make_float4(r0.x + r1.x + r2.x + r3.x,
                                           r0.y + r1.y + r2.y + r3.y,
                                           r0.z + r1.z + r2.z + r3.z,
                                           r0.w + r1.w + r2.w + r3.w);
    }
}

__global__ __launch_bounds__(256) void splloss_final(
    const float4* __restrict__ partials, int nb, float* __restrict__ out,
    double inv_bs, double inv_bd, double inv_shape)
{
    double o = 0.0, m = 0.0, t = 0.0, s = 0.0;
    for (int i = threadIdx.x; i < nb; i += 256) {
        float4 p = partials[i];
        o += (double)p.x; m += (double)p.y; t += (double)p.z; s += (double)p.w;
    }
    #pragma unroll
    for (int off = 32; off > 0; off >>= 1) {
        o += __shfl_down(o, off);
        m += __shfl_down(m, off);
        t += __shfl_down(t, off);
        s += __shfl_down(s, off);
    }
    __shared__ double red[4][4];
    int wid = threadIdx.x >> 6;
    if ((threadIdx.x & 63) == 0) { red[wid][0] = o; red[wid][1] = m; red[wid][2] = t; red[wid][3] = s; }
    __syncthreads();
    if (threadIdx.x == 0) {
        double ot = red[0][0] + red[1][0] + red[2][0] + red[3][0];
        double mt = red[0][1] + red[1][1] + red[2][1] + red[3][1];
        double tt = red[0][2] + red[1][2] + red[2][2] + red[3][2];
        double st = red[0][3] + red[1][3] + red[2][3] + red[3][3];
        double total = 1.0 * (ot * inv_bs)
                     + 2.0 * (mt * inv_bd)
                     + 1.0 * (tt * inv_bd)
                     + 0.5 * (st * inv_shape);
        out[0] = (float)total;
    }
}

extern "C" void kernel_launch(void* const* d_in, const int* in_sizes, int n_in,
                              void* d_out, int out_size, void* d_ws, size_t ws_size,
                              hipStream_t stream) {
    const float* yp = (const float*)d_in[0];
    const float* yt = (const float*)d_in[1];
    const float* dm = (const float*)d_in[2];
    float* out = (float*)d_out;

    int n = in_sizes[0];              // B*S; S divisible by 24
    int n_days = n / HOURS_;          // B*D

    // 64 days per block per iteration (4 lanes/day, 256 threads).
    // 1536 blocks = 6 blocks/CU fully resident; bench shape -> nit = 10 exact.
    int nb = (n_days + 63) / 64;
    if (nb > 1536) nb = 1536;
    int perIter = nb * 64;
    int nit = (n_days + perIter - 1) / perIter;

    float4* partials = (float4*)d_ws; // nb * 16 bytes

    splloss_days<<<nb, 256, 0, stream>>>(yp, yt, dm, partials, n_days, nit);

    double inv_bs    = 1.0 / (double)n;
    double inv_bd    = 1.0 / (double)n_days;
    double inv_shape = 1.0 / ((double)n_days + 1e-6);
    splloss_final<<<1, 256, 0, stream>>>(partials, nb, out, inv_bs, inv_bd, inv_shape);
}

// Round 10
// 272.566 us; speedup vs baseline: 1.0397x; 1.0397x over previous
//
#include <hip/hip_runtime.h>
#include <math.h>

// SoftPeakAwareLoss on MI355X — R8 resubmit (R8 bench hit GPU-acquisition
// timeout, never measured): R7 structure, spill-free + pinned prefetch.
// R7 evidence: occupancy 33->55% and demand BW 2.7->3.3 TB/s with persistent
// blocks (direction right), but launch_bounds(256,6) capped VGPR at ~85 and
// the 2-deep prefetch spilled (VGPR=40, WRITE_SIZE 58.8MB scratch) -> +42%
// traffic -> regression. R8: no min-waves clamp, 1-deep prefetch whose values
// cross the loop backedge (load iter k+1 before computing iter k), pinned
// with one sched_barrier(0) so loads can't sink to their use. DPP quad
// butterflies and all math identical to R7 (validated absmax 0.0).

#define HOURS_ 24
#define WIN_ 2
#define NEGV (-1e9f)

__device__ __forceinline__ float frcp(float x) { return __builtin_amdgcn_rcpf(x); }

#define DPP_XOR1 0xB1   // quad_perm [1,0,3,2]
#define DPP_XOR2 0x4E   // quad_perm [2,3,0,1]

template<int CTRL>
__device__ __forceinline__ int dpp_i(int src) {
    return __builtin_amdgcn_update_dpp(0, src, CTRL, 0xF, 0xF, true);
}
template<int CTRL>
__device__ __forceinline__ float dpp_f(float x) {
    return __int_as_float(dpp_i<CTRL>(__float_as_int(x)));
}

// One 6-hour segment of one day; lanes (l&3)==0..3 own segments 0..3 and
// combine via DPP quad butterflies. Identical math to R7 (absmax 0.0).
__device__ __forceinline__ void seg_body(
    float2 p0, float2 p1, float2 p2,
    float2 t0, float2 t1, float2 t2,
    float2 m0, float2 m1, float2 m2,
    int seg, float vfl,
    float& o, float& mg, float& tl, float& sh)
{
    const int h0 = seg * 6;
    float a[6]  = {p0.x, p0.y, p1.x, p1.y, p2.x, p2.y};
    float b[6]  = {t0.x, t0.y, t1.x, t1.y, t2.x, t2.y};
    float dm[6] = {m0.x, m0.y, m1.x, m1.y, m2.x, m2.y};

    // ---- L_overall partial (own hours only)
    float oo = 0.f;
    #pragma unroll
    for (int k = 0; k < 6; ++k) { float d = a[k] - b[k]; oo = fmaf(d, d, oo); }
    o = fmaf(oo, vfl, o);

    // ---- masked values
    float bm[6], am[6];
    #pragma unroll
    for (int k = 0; k < 6; ++k) {
        bool dy = dm[k] > 0.5f;
        bm[k] = dy ? b[k] : NEGV;
        am[k] = dy ? a[k] : NEGV;
    }

    // ---- local first-occurrence argmax over 6 (ordered tree, strict >)
    bool  s0 = bm[1] > bm[0]; float v01 = s0 ? bm[1] : bm[0]; int i01 = s0 ? h0+1 : h0;
    bool  s1 = bm[3] > bm[2]; float v23 = s1 ? bm[3] : bm[2]; int i23 = s1 ? h0+3 : h0+2;
    bool  s2 = bm[5] > bm[4]; float v45 = s2 ? bm[5] : bm[4]; int i45 = s2 ? h0+5 : h0+4;
    bool  tA = v23 > v01; float mt = tA ? v23 : v01; int pk = tA ? i23 : i01;
    bool  tB = v45 > mt;  mt = tB ? v45 : mt;        pk = tB ? i45 : pk;
    float mp = fmaxf(fmaxf(fmaxf(am[0], am[1]), fmaxf(am[2], am[3])),
                     fmaxf(am[4], am[5]));

    // ---- quad butterfly (VALU-speed DPP; ties -> lower hour)
    {
        float mt_o = dpp_f<DPP_XOR1>(mt); int pk_o = dpp_i<DPP_XOR1>(pk);
        float mp_o = dpp_f<DPP_XOR1>(mp);
        bool to = (mt_o > mt) || (mt_o == mt && pk_o < pk);
        pk = to ? pk_o : pk; mt = fmaxf(mt, mt_o); mp = fmaxf(mp, mp_o);
        mt_o = dpp_f<DPP_XOR2>(mt); pk_o = dpp_i<DPP_XOR2>(pk);
        mp_o = dpp_f<DPP_XOR2>(mp);
        to = (mt_o > mt) || (mt_o == mt && pk_o < pk);
        pk = to ? pk_o : pk; mt = fmaxf(mt, mt_o); mp = fmaxf(mp, mp_o);
    }

    // ---- soft peaks: exp((x-m)*10); night -> exp(-1e10)=0
    float mt10 = mt * 10.f, mp10 = mp * 10.f;
    float set = 0.f, syt = 0.f, sht = 0.f;
    float sep = 0.f, syp = 0.f, shp = 0.f;
    #pragma unroll
    for (int k = 0; k < 6; ++k) {
        float et = __expf(fmaf(bm[k], 10.f, -mt10));
        float ep = __expf(fmaf(am[k], 10.f, -mp10));
        float hh = (float)(h0 + k);
        set += et; syt = fmaf(et, b[k], syt); sht = fmaf(et, hh, sht);
        sep += ep; syp = fmaf(ep, a[k], syp); shp = fmaf(ep, hh, shp);
    }
    set += dpp_f<DPP_XOR1>(set); set += dpp_f<DPP_XOR2>(set);
    syt += dpp_f<DPP_XOR1>(syt); syt += dpp_f<DPP_XOR2>(syt);
    sht += dpp_f<DPP_XOR1>(sht); sht += dpp_f<DPP_XOR2>(sht);
    sep += dpp_f<DPP_XOR1>(sep); sep += dpp_f<DPP_XOR2>(sep);
    syp += dpp_f<DPP_XOR1>(syp); syp += dpp_f<DPP_XOR2>(syp);
    shp += dpp_f<DPP_XOR1>(shp); shp += dpp_f<DPP_XOR2>(shp);
    {
        float rs = frcp(set), rq = frcp(sep);
        float d1 = syp * rq - syt * rs;
        float d2 = shp * rq - sht * rs;
        float once = (seg == 0) ? vfl : 0.f;   // count each day once
        mg = fmaf(d1 * d1, once, mg);
        tl = fmaf(d2 * d2, once, tl);
    }

    // ---- shape loss: window [pk-2, pk+2] clipped; analytic exact 1/cnt
    int lo = pk - WIN_; lo = lo < 0 ? 0 : lo;
    int hi = pk + WIN_; hi = hi > 23 ? 23 : hi;
    int cnt = hi - lo + 1;                      // 3,4,5
    float invcnt = (cnt == 5) ? 0.2f : ((cnt == 4) ? 0.25f : (1.f / 3.f));
    float twm = -INFINITY, pwm = -INFINITY;
    #pragma unroll
    for (int k = 0; k < 6; ++k) {
        int hg = h0 + k;
        bool in = (hg >= lo) && (hg <= hi);
        twm = in ? fmaxf(twm, b[k]) : twm;
        pwm = in ? fmaxf(pwm, a[k]) : pwm;
    }
    twm = fmaxf(twm, dpp_f<DPP_XOR1>(twm)); twm = fmaxf(twm, dpp_f<DPP_XOR2>(twm));
    pwm = fmaxf(pwm, dpp_f<DPP_XOR1>(pwm)); pwm = fmaxf(pwm, dpp_f<DPP_XOR2>(pwm));
    {
        float rt = frcp(twm + 1e-6f);
        float rp = frcp(pwm + 1e-6f);
        float ss = 0.f;
        #pragma unroll
        for (int k = 0; k < 6; ++k) {
            int hg = h0 + k;
            bool in = (hg >= lo) && (hg <= hi);
            float d = fmaf(a[k], rp, -(b[k] * rt));
            ss = in ? fmaf(d, d, ss) : ss;
        }
        sh = fmaf(ss * invcnt, vfl, sh);
    }
}

__global__ __launch_bounds__(256) void splloss_days(
    const float* __restrict__ ypred,
    const float* __restrict__ ytrue,
    const float* __restrict__ isday,
    float4* __restrict__ partials,
    int n_days, int nit)
{
    const int tid = threadIdx.x;
    const int seg = tid & 3;             // 6-hour segment within the day
    const int grp = tid >> 2;            // day-slot within block: 0..63
    const int dayStride = gridDim.x * 64;
    const int segOff = seg * 6;

    int day = blockIdx.x * 64 + grp;

    float o = 0.f, mg = 0.f, tl = 0.f, sh = 0.f;

    // ---- prologue: load iter 0 into the current buffer
    int   dA = day < n_days ? day : 0;
    float vA = day < n_days ? 1.f : 0.f;
    {
        const float2* p = reinterpret_cast<const float2*>(ypred + (size_t)dA * 24 + segOff);
        const float2* t = reinterpret_cast<const float2*>(ytrue + (size_t)dA * 24 + segOff);
        const float2* m = reinterpret_cast<const float2*>(isday + (size_t)dA * 24 + segOff);
        // current buffer
        float2 a0 = p[0], a1 = p[1], a2 = p[2];
        float2 b0 = t[0], b1 = t[1], b2 = t[2];
        float2 c0 = m[0], c1 = m[1], c2 = m[2];

        for (int it = 0; it < nit; ++it) {
            // ---- prefetch next iteration (values cross the loop backedge)
            int   dayN = day + dayStride;
            int   dB = dayN < n_days ? dayN : 0;
            float vB = dayN < n_days ? 1.f : 0.f;
            const float2* pN = reinterpret_cast<const float2*>(ypred + (size_t)dB * 24 + segOff);
            const float2* tN = reinterpret_cast<const float2*>(ytrue + (size_t)dB * 24 + segOff);
            const float2* mN = reinterpret_cast<const float2*>(isday + (size_t)dB * 24 + segOff);
            float2 e0 = pN[0], e1 = pN[1], e2 = pN[2];
            float2 f0 = tN[0], f1 = tN[1], f2 = tN[2];
            float2 g0 = mN[0], g1 = mN[1], g2 = mN[2];
            // pin the prefetch issue above the compute body
            __builtin_amdgcn_sched_barrier(0);

            // ---- compute current day (covers the prefetch latency)
            seg_body(a0, a1, a2, b0, b1, b2, c0, c1, c2, seg, vA, o, mg, tl, sh);

            // ---- rotate (compiler renames; waitcnt for e..g lands here)
            a0 = e0; a1 = e1; a2 = e2;
            b0 = f0; b1 = f1; b2 = f2;
            c0 = g0; c1 = g1; c2 = g2;
            vA = vB; day = dayN;
        }
    }

    // ---- block reduction: wave shuffle then LDS across the 4 waves
    #pragma unroll
    for (int off = 32; off > 0; off >>= 1) {
        o  += __shfl_down(o,  off);
        mg += __shfl_down(mg, off);
        tl += __shfl_down(tl, off);
        sh += __shfl_down(sh, off);
    }
    __shared__ float4 red[4];
    int wid = threadIdx.x >> 6;
    if ((threadIdx.x & 63) == 0) red[wid] = make_float4(o, mg, tl, sh);
    __syncthreads();
    if (threadIdx.x == 0) {
        float4 r0 = red[0], r1 = red[1], r2 = red[2], r3 = red[3];
        partials[blockIdx.x] = make_float4(r0.x + r1.x + r2.x + r3.x,
                                           r0.y + r1.y + r2.y + r3.y,
                                           r0.z + r1.z + r2.z + r3.z,
                                           r0.w + r1.w + r2.w + r3.w);
    }
}

__global__ __launch_bounds__(256) void splloss_final(
    const float4* __restrict__ partials, int nb, float* __restrict__ out,
    double inv_bs, double inv_bd, double inv_shape)
{
    double o = 0.0, m = 0.0, t = 0.0, s = 0.0;
    for (int i = threadIdx.x; i < nb; i += 256) {
        float4 p = partials[i];
        o += (double)p.x; m += (double)p.y; t += (double)p.z; s += (double)p.w;
    }
    #pragma unroll
    for (int off = 32; off > 0; off >>= 1) {
        o += __shfl_down(o, off);
        m += __shfl_down(m, off);
        t += __shfl_down(t, off);
        s += __shfl_down(s, off);
    }
    __shared__ double red[4][4];
    int wid = threadIdx.x >> 6;
    if ((threadIdx.x & 63) == 0) { red[wid][0] = o; red[wid][1] = m; red[wid][2] = t; red[wid][3] = s; }
    __syncthreads();
    if (threadIdx.x == 0) {
        double ot = red[0][0] + red[1][0] + red[2][0] + red[3][0];
        double mt = red[0][1] + red[1][1] + red[2][1] + red[3][1];
        double tt = red[0][2] + red[1][2] + red[2][2] + red[3][2];
        double st = red[0][3] + red[1][3] + red[2][3] + red[3][3];
        double total = 1.0 * (ot * inv_bs)
                     + 2.0 * (mt * inv_bd)
                     + 1.0 * (tt * inv_bd)
                     + 0.5 * (st * inv_shape);
        out[0] = (float)total;
    }
}

extern "C" void kernel_launch(void* const* d_in, const int* in_sizes, int n_in,
                              void* d_out, int out_size, void* d_ws, size_t ws_size,
                              hipStream_t stream) {
    const float* yp = (const float*)d_in[0];
    const float* yt = (const float*)d_in[1];
    const float* dm = (const float*)d_in[2];
    float* out = (float*)d_out;

    int n = in_sizes[0];              // B*S; S divisible by 24
    int n_days = n / HOURS_;          // B*D

    // 64 days per block per iteration (4 lanes/day, 256 threads).
    // 1536 persistent blocks (6/CU); bench shape -> nit = 10 exact.
    int nb = (n_days + 63) / 64;
    if (nb > 1536) nb = 1536;
    int perIter = nb * 64;
    int nit = (n_days + perIter - 1) / perIter;

    float4* partials = (float4*)d_ws; // nb * 16 bytes

    splloss_days<<<nb, 256, 0, stream>>>(yp, yt, dm, partials, n_days, nit);

    double inv_bs    = 1.0 / (double)n;
    double inv_bd    = 1.0 / (double)n_days;
    double inv_shape = 1.0 / ((double)n_days + 1e-6);
    splloss_final<<<1, 256, 0, stream>>>(partials, nb, out, inv_bs, inv_bd, inv_shape);
}